// Round 6
// baseline (946.249 us; speedup 1.0000x reference)
//
#include <hip/hip_runtime.h>

typedef __attribute__((ext_vector_type(8))) short short8v;
typedef __attribute__((ext_vector_type(8))) unsigned short ushort8v;
typedef __attribute__((ext_vector_type(4))) float float4v;

__device__ __constant__ float c_LO[8] = {
    -0.010597401784997278f, 0.032883011666982945f, 0.030841381835986965f,
    -0.18703481171888114f, -0.02798376941698385f, 0.6308807679295904f,
    0.7148465705525415f, 0.23037781330885523f};
__device__ __constant__ float c_HI[8] = {
    -0.23037781330885523f, 0.7148465705525415f, -0.6308807679295904f,
    -0.02798376941698385f, 0.18703481171888114f, 0.030841381835986965f,
    -0.032883011666982945f, -0.010597401784997278f};

__device__ __forceinline__ unsigned short f2bf(float f) {
    unsigned u = __builtin_bit_cast(unsigned, f);
    unsigned r = u + 0x7fffu + ((u >> 16) & 1u);
    return (unsigned short)(r >> 16);
}
__device__ __forceinline__ float bf2f(unsigned short u) {
    return __builtin_bit_cast(float, (unsigned)u << 16);
}

// tanh-form GELU: one exp2 + rcp
__device__ __forceinline__ float gelu_fast(float x) {
    float x3 = x * x * x;
    float y = fmaf(0.044715f, x3, x) * 0.7978845608028654f;
    float t = fminf(fmaxf(y * 2.8853900817779268f, -30.f), 30.f);
    float e = exp2f(t);
    return x * e * __builtin_amdgcn_rcpf(e + 1.0f);
}

__device__ __forceinline__ void gload_lds16(const void* g, void* l) {
    __builtin_amdgcn_global_load_lds(g, l, 16, 0, 0);
}

// ---------------- x -> bf16 cast ----------------
__global__ void cast_bf16_kernel(const float* __restrict__ in, unsigned short* __restrict__ out, int n4) {
    int i = blockIdx.x * blockDim.x + threadIdx.x;
    if (i >= n4) return;
    float4 v = ((const float4*)in)[i];
    ushort4 o;
    o.x = f2bf(v.x); o.y = f2bf(v.y); o.z = f2bf(v.z); o.w = f2bf(v.w);
    ((ushort4*)out)[i] = o;
}

// ---------------- CSR build: histogram ----------------
__global__ void hist_kernel(const int* __restrict__ rows, int* __restrict__ cnt, int E) {
    int i = blockIdx.x * blockDim.x + threadIdx.x;
    if (i < E) atomicAdd(&cnt[rows[i]], 1);
}

// ---------------- CSR build: single-block scan ----------------
__global__ __launch_bounds__(1024) void scan_kernel(const int* __restrict__ cnt, int* __restrict__ offs,
                                                    int* __restrict__ cursor, int Nrows, int E) {
    __shared__ int part[1024];
    int tid = threadIdx.x;
    const int per = Nrows / 1024;  // 16
    int base = tid * per;
    int local[16];
    int s = 0;
    for (int i = 0; i < per; ++i) { local[i] = s; s += cnt[base + i]; }
    part[tid] = s;
    __syncthreads();
    for (int off = 1; off < 1024; off <<= 1) {
        int v = part[tid];
        int w = (tid >= off) ? part[tid - off] : 0;
        __syncthreads();
        part[tid] = v + w;
        __syncthreads();
    }
    int pre = (tid == 0) ? 0 : part[tid - 1];
    for (int i = 0; i < per; ++i) {
        int o = pre + local[i];
        offs[base + i] = o;
        cursor[base + i] = o;
    }
    if (tid == 0) offs[Nrows] = E;
}

// ---------------- CSR build: scatter ----------------
__global__ void scatter_kernel(const int* __restrict__ rows, const int* __restrict__ cols,
                               const float* __restrict__ vals, int* __restrict__ cursor,
                               int* __restrict__ ccol, float* __restrict__ cval, int E) {
    int i = blockIdx.x * blockDim.x + threadIdx.x;
    if (i >= E) return;
    int r = rows[i];
    int p = atomicAdd(&cursor[r], 1);
    ccol[p] = cols[i];
    cval[p] = vals[i];
}

// ---------------- SpMM CSR: one wave per row, bf16 gather ----------------
__global__ __launch_bounds__(256) void spmm_csr(const unsigned short* __restrict__ xb, const int* __restrict__ offs,
                                                const int* __restrict__ ccol, const float* __restrict__ cval,
                                                float* __restrict__ xa) {
    int r = blockIdx.x * 4 + (threadIdx.x >> 6);
    int lane = threadIdx.x & 63;
    int s = offs[r], e = offs[r + 1];
    float acc[12] = {};
    for (int j = s; j < e; ++j) {
        int c = ccol[j];
        float v = cval[j];
        const unsigned short* xr = xb + (size_t)c * 768;
#pragma unroll
        for (int seg = 0; seg < 3; ++seg) {
            ushort4 u = *(const ushort4*)(xr + seg * 256 + lane * 4);
            acc[seg * 4 + 0] = fmaf(v, bf2f(u.x), acc[seg * 4 + 0]);
            acc[seg * 4 + 1] = fmaf(v, bf2f(u.y), acc[seg * 4 + 1]);
            acc[seg * 4 + 2] = fmaf(v, bf2f(u.z), acc[seg * 4 + 2]);
            acc[seg * 4 + 3] = fmaf(v, bf2f(u.w), acc[seg * 4 + 3]);
        }
    }
    float* o = xa + (size_t)r * 768;
#pragma unroll
    for (int seg = 0; seg < 3; ++seg) {
        float4 w = make_float4(acc[seg * 4], acc[seg * 4 + 1], acc[seg * 4 + 2], acc[seg * 4 + 3]);
        *(float4*)(o + seg * 256 + lane * 4) = w;
    }
}

// ---------------- one DWT level (pywt symmetric) ----------------
template <bool IN_BF16, bool A_BF16>
__global__ void dwt_kernel(const void* __restrict__ in, int n, int in_stride,
                           void* __restrict__ outA, int a_stride,
                           unsigned short* __restrict__ outD, int d_stride, int m) {
    extern __shared__ float srow[];
    int row = blockIdx.x;
    if (IN_BF16) {
        const unsigned short* ip = (const unsigned short*)in + (size_t)row * in_stride;
        for (int i = threadIdx.x; i < n; i += blockDim.x) srow[i] = bf2f(ip[i]);
    } else {
        const float* ip = (const float*)in + (size_t)row * in_stride;
        for (int i = threadIdx.x; i < n; i += blockDim.x) srow[i] = ip[i];
    }
    __syncthreads();
    for (int j = threadIdx.x; j < m; j += blockDim.x) {
        float a = 0.f, d = 0.f;
#pragma unroll
        for (int i = 0; i < 8; ++i) {
            int p = 2 * j + 7 - i;
            int q = (p < 6) ? (5 - p) : ((p < n + 6) ? (p - 6) : (2 * n + 5 - p));
            float xv = srow[q];
            a = fmaf(c_LO[i], xv, a);
            d = fmaf(c_HI[i], xv, d);
        }
        if (A_BF16)
            ((unsigned short*)outA)[(size_t)row * a_stride + j] = f2bf(a);
        else
            ((float*)outA)[(size_t)row * a_stride + j] = a;
        outD[(size_t)row * d_stride + j] = f2bf(d);
    }
}

// ---------------- pack basis stack -> transposed bf16 [N][Kpad] ----------------
struct Bounds { int b[6]; };

__global__ void pack_basis_T(const float* __restrict__ basis, unsigned short* __restrict__ BT,
                             Bounds bd, int brows, int N, int K, int Kpad) {
    int idx = blockIdx.x * blockDim.x + threadIdx.x;
    if (idx >= N * Kpad) return;
    int n = idx / Kpad, k = idx - n * Kpad;
    float v = 0.f;
    if (k < K) {
        int s = 0;
#pragma unroll
        for (int t = 1; t < 5; ++t)
            if (k >= bd.b[t]) s = t;
        int lr = k - bd.b[s];
        v = basis[((size_t)s * brows + lr) * N + n];
    }
    BT[idx] = f2bf(v);
}

// ---------------- pack weights [NB][K][N] -> transposed bf16 [NB][N][Kpad] ----------------
__global__ void pack_wT(const float* __restrict__ W, unsigned short* __restrict__ WT,
                        int NB, int K, int N, int Kpad) {
    int idx = blockIdx.x * blockDim.x + threadIdx.x;
    int tot = NB * N * Kpad;
    if (idx >= tot) return;
    int b = idx / (N * Kpad);
    int r = idx - b * (N * Kpad);
    int n = r / Kpad, k = r - n * Kpad;
    float v = (k < K) ? W[((size_t)b * K + k) * N + n] : 0.f;
    WT[idx] = f2bf(v);
}

// ---------------- bf16 MFMA GEMM (unchanged, proven) ----------------
template <int OUT_BF16>
__global__ __launch_bounds__(256) void gemm_mfma(const unsigned short* __restrict__ A,
                                                 const unsigned short* __restrict__ BT,
                                                 const float* __restrict__ bias,
                                                 void* __restrict__ Cv,
                                                 int M, int N, int K, int lda, int ldb, int ldc) {
    __shared__ __align__(16) unsigned short As[128 * 32];
    __shared__ __align__(16) unsigned short Bs[128 * 32];
    const int tid = threadIdx.x;
    const int wave = tid >> 6, lane = tid & 63;
    const int m0 = blockIdx.y * 128, n0 = blockIdx.x * 128;
    const int wr = wave >> 1, wc = wave & 1;
    const int frow = lane & 15, fq = lane >> 4;

    const int off0 = tid * 16;
    const int r0 = off0 >> 6, c0 = off0 & 63;
    const int r1 = (off0 + 4096) >> 6, c1 = (off0 + 4096) & 63;
    const char* Ab = (const char*)A;
    const char* Bb = (const char*)BT;
    size_t gA0 = (size_t)(m0 + r0) * lda * 2 + c0;
    size_t gA1 = (size_t)(m0 + r1) * lda * 2 + c1;
    size_t gB0 = (size_t)(n0 + r0) * ldb * 2 + c0;
    size_t gB1 = (size_t)(n0 + r1) * ldb * 2 + c1;
    char* lA0 = (char*)As + wave * 1024;
    char* lB0 = (char*)Bs + wave * 1024;

    const int aoff = (wr * 64 + frow) * 32 + fq * 8;
    const int boff = (wc * 64 + frow) * 32 + fq * 8;

    float4v acc[4][4] = {};
    for (int k0 = 0; k0 < K; k0 += 32) {
        size_t kb2 = (size_t)k0 * 2;
        gload_lds16(Ab + gA0 + kb2, lA0);
        gload_lds16(Ab + gA1 + kb2, lA0 + 4096);
        gload_lds16(Bb + gB0 + kb2, lB0);
        gload_lds16(Bb + gB1 + kb2, lB0 + 4096);
        __syncthreads();
        short8v av[4], bv[4];
#pragma unroll
        for (int i = 0; i < 4; ++i) av[i] = *(const short8v*)(As + aoff + i * 512);
#pragma unroll
        for (int i = 0; i < 4; ++i) bv[i] = *(const short8v*)(Bs + boff + i * 512);
#pragma unroll
        for (int mi = 0; mi < 4; ++mi)
#pragma unroll
            for (int ni = 0; ni < 4; ++ni)
                acc[mi][ni] = __builtin_amdgcn_mfma_f32_16x16x32_bf16(av[mi], bv[ni], acc[mi][ni], 0, 0, 0);
        __syncthreads();
    }
#pragma unroll
    for (int ni = 0; ni < 4; ++ni) {
        int col = n0 + wc * 64 + ni * 16 + frow;
        float bval = bias ? bias[col] : 0.f;
#pragma unroll
        for (int mi = 0; mi < 4; ++mi) {
#pragma unroll
            for (int i = 0; i < 4; ++i) {
                int row = m0 + wr * 64 + mi * 16 + fq * 4 + i;
                float v = acc[mi][ni][i] + bval;
                if (OUT_BF16)
                    ((unsigned short*)Cv)[(size_t)row * ldc + col] = f2bf(v);
                else
                    ((float*)Cv)[(size_t)row * ldc + col] = v;
            }
        }
    }
}

// ---- dendritic fused v2: A-resident LDS; B 3-slot ring, 2-ahead prefetch, counted vmcnt ----
template <int KTILE>
__global__ __launch_bounds__(256) void dendritic_fused(const unsigned short* __restrict__ A,
                                                       const unsigned short* __restrict__ WT,
                                                       const float* __restrict__ bias,
                                                       unsigned short* __restrict__ out,
                                                       int Nc, int nb) {
    constexpr int KS = KTILE / 32;
    constexpr int KB = KTILE * 2;
    __shared__ __align__(16) unsigned short Atile[128 * KTILE];
    __shared__ __align__(16) unsigned short Bt[3 * 128 * 32];
    const int tid = threadIdx.x;
    const int wave = tid >> 6, lane = tid & 63;
    const int m0 = blockIdx.y * 128, n0 = blockIdx.x * 128;
    const int wr = wave >> 1, wc = wave & 1;
    const int frow = lane & 15, fq = lane >> 4;

    // B staging: linear LDS dest, source pre-swizzled (col ^= (row&3)<<4)
    const int off0 = tid * 16;
    const int brow0 = off0 >> 6, bcb0 = off0 & 63;
    const int off1 = off0 + 4096;
    const int brow1 = off1 >> 6, bcb1 = off1 & 63;
    const size_t bsrc0 = (size_t)(n0 + brow0) * KB + (bcb0 ^ ((brow0 & 3) << 4));
    const size_t bsrc1 = (size_t)(n0 + brow1) * KB + (bcb1 ^ ((brow1 & 3) << 4));
    const char* WTb = (const char*)WT;
    const size_t branchBytes = (size_t)Nc * KB;
    const int T = nb * KS;

    auto issueB = [&](int tt, int slot) {
        int kb_ = tt / KS, ks_ = tt - kb_ * KS;
        const char* Bb_ = WTb + (size_t)kb_ * branchBytes + (size_t)ks_ * 64;
        char* db_ = (char*)Bt + slot * 8192 + wave * 1024;
        gload_lds16(Bb_ + bsrc0, db_);
        gload_lds16(Bb_ + bsrc1, db_ + 4096);
    };

    issueB(0, 0);
    issueB(1, 1);

    // stage A tile once, XOR-swizzled (byte col ^= (row&7)<<4)
    {
        constexpr int CPR = KTILE / 8;  // 16B chunks per row
#pragma unroll
        for (int i = 0; i < 128 * CPR / 256; ++i) {
            int ch = tid + i * 256;
            int row = ch / CPR;
            int cb = (ch - row * CPR) * 16;
            ushort8v v = *(const ushort8v*)(A + (size_t)(m0 + row) * KTILE + cb / 2);
            *(ushort8v*)((char*)Atile + row * KB + (cb ^ ((row & 7) << 4))) = v;
        }
    }
    __syncthreads();  // drains A ds_writes + B tiles 0,1 (vmcnt -> 0)

    int raBy[4], rbBy[4];
#pragma unroll
    for (int mi = 0; mi < 4; ++mi) raBy[mi] = (wr * 64 + mi * 16 + frow) * KB;
#pragma unroll
    for (int ni = 0; ni < 4; ++ni) {
        int rb = wc * 64 + ni * 16 + frow;
        rbBy[ni] = rb * 64 + ((fq * 16) ^ ((rb & 3) << 4));
    }

    float4v acc[4][4] = {};
    float4v best[4][4];
#pragma unroll
    for (int mi = 0; mi < 4; ++mi)
#pragma unroll
        for (int ni = 0; ni < 4; ++ni) best[mi][ni] = (float4v)(-1e30f);

    for (int t = 0; t < T; ++t) {
        const int kb = t / KS, ks = t - kb * KS;
        const int slot = t % 3;
        // tile t's loads are the 3rd-newest pair at worst -> vmcnt(2) guarantees landed
        asm volatile("s_waitcnt vmcnt(2)" ::: "memory");
        __builtin_amdgcn_s_barrier();          // all waves' quarters of tile t landed; slot (t+2)%3 free
        __builtin_amdgcn_sched_barrier(0);
        if (t + 2 < T) issueB(t + 2, (t + 2) % 3);

        short8v av[4], bv[4];
        const int kcol = ks * 64 + fq * 16;
#pragma unroll
        for (int mi = 0; mi < 4; ++mi) {
            int ra = wr * 64 + mi * 16 + frow;
            av[mi] = *(const short8v*)((const char*)Atile + raBy[mi] + (kcol ^ ((ra & 7) << 4)));
        }
#pragma unroll
        for (int ni = 0; ni < 4; ++ni)
            bv[ni] = *(const short8v*)((const char*)Bt + slot * 8192 + rbBy[ni]);
#pragma unroll
        for (int mi = 0; mi < 4; ++mi)
#pragma unroll
            for (int ni = 0; ni < 4; ++ni)
                acc[mi][ni] = __builtin_amdgcn_mfma_f32_16x16x32_bf16(av[mi], bv[ni], acc[mi][ni], 0, 0, 0);

        if (ks == KS - 1) {
#pragma unroll
            for (int ni = 0; ni < 4; ++ni) {
                int col = n0 + wc * 64 + ni * 16 + frow;
                float bval = bias[kb * Nc + col];
#pragma unroll
                for (int mi = 0; mi < 4; ++mi) {
#pragma unroll
                    for (int i = 0; i < 4; ++i) {
                        float v = acc[mi][ni][i] + bval;
                        best[mi][ni][i] = fmaxf(best[mi][ni][i], gelu_fast(v));
                        acc[mi][ni][i] = 0.f;
                    }
                }
            }
        }
    }

#pragma unroll
    for (int ni = 0; ni < 4; ++ni) {
        int col = n0 + wc * 64 + ni * 16 + frow;
#pragma unroll
        for (int mi = 0; mi < 4; ++mi) {
#pragma unroll
            for (int i = 0; i < 4; ++i) {
                int row = m0 + wr * 64 + mi * 16 + fq * 4 + i;
                out[(size_t)row * Nc + col] = f2bf(best[mi][ni][i]);
            }
        }
    }
}

// ---------------- LayerNorm over H=512: f32 in -> bf16 out ----------------
__global__ __launch_bounds__(256) void layernorm_bf16(const float* __restrict__ h,
                                                      unsigned short* __restrict__ o,
                                                      const float* __restrict__ g,
                                                      const float* __restrict__ b) {
    int row = blockIdx.x;
    const float* p = h + (size_t)row * 512;
    int tid = threadIdx.x;
    float v0 = p[tid], v1 = p[tid + 256];
    float s = v0 + v1, sq = v0 * v0 + v1 * v1;
#pragma unroll
    for (int off = 32; off >= 1; off >>= 1) {
        s += __shfl_xor(s, off);
        sq += __shfl_xor(sq, off);
    }
    __shared__ float ls[4], lq[4];
    int wid = tid >> 6, lane = tid & 63;
    if (lane == 0) { ls[wid] = s; lq[wid] = sq; }
    __syncthreads();
    float ts = ls[0] + ls[1] + ls[2] + ls[3];
    float tq = lq[0] + lq[1] + lq[2] + lq[3];
    float mean = ts / 512.f;
    float var = tq / 512.f - mean * mean;
    float inv = rsqrtf(var + 1e-5f);
    unsigned short* op = o + (size_t)row * 512;
    op[tid] = f2bf((v0 - mean) * inv * g[tid] + b[tid]);
    op[tid + 256] = f2bf((v1 - mean) * inv * g[tid + 256] + b[tid + 256]);
}

// ---------------- z = mu + eps * exp(0.5*logvar)  -> bf16 ----------------
__global__ void z_kernel(const float* __restrict__ mu, const float* __restrict__ lv,
                         const float* __restrict__ eps, unsigned short* __restrict__ z, int n4) {
    int i = blockIdx.x * blockDim.x + threadIdx.x;
    if (i >= n4) return;
    float4 m = ((const float4*)mu)[i];
    float4 l = ((const float4*)lv)[i];
    float4 e = ((const float4*)eps)[i];
    ushort4 o;
    o.x = f2bf(m.x + e.x * expf(0.5f * l.x));
    o.y = f2bf(m.y + e.y * expf(0.5f * l.y));
    o.z = f2bf(m.z + e.z * expf(0.5f * l.z));
    o.w = f2bf(m.w + e.w * expf(0.5f * l.w));
    ((ushort4*)z)[i] = o;
}

extern "C" void kernel_launch(void* const* d_in, const int* in_sizes, int n_in,
                              void* d_out, int out_size, void* d_ws, size_t ws_size,
                              hipStream_t stream) {
    const float* x        = (const float*)d_in[0];
    const int*   arows    = (const int*)d_in[1];
    const int*   acols    = (const int*)d_in[2];
    const float* avals    = (const float*)d_in[3];
    const float* basisenc = (const float*)d_in[4];
    const float* ln_g     = (const float*)d_in[5];
    const float* ln_b     = (const float*)d_in[6];
    const float* Wd_enc   = (const float*)d_in[7];
    const float* bd_enc   = (const float*)d_in[8];
    const float* W_mu     = (const float*)d_in[9];
    const float* b_mu     = (const float*)d_in[10];
    const float* W_lv     = (const float*)d_in[11];
    const float* b_lv     = (const float*)d_in[12];
    const float* Wd_dec   = (const float*)d_in[13];
    const float* bd_dec   = (const float*)d_in[14];
    const float* basisdec = (const float*)d_in[15];
    const float* epsin    = (const float*)d_in[16];

    const int N = 16384;
    const int E = in_sizes[1];

    float* ws = (float*)d_ws;
    const size_t A0 = 0;                               // f32 N*768: xa -> hF -> b1
    const size_t B0 = A0 + (size_t)N * 768;            // u16 N*800: cenc -> [cdec | zb]
    const size_t C0 = B0 + (size_t)N * 400;            // f32 N*387: xbf(u16 N*768) -> a1 -> [hbf|encb] -> decb
    const size_t D0 = C0 + (size_t)N * 387;            // f32 N*197: a2 -> b2
    const size_t E0 = D0 + (size_t)N * 197;            // f32 N*102: a3 -> b3
    const size_t F0 = E0 + (size_t)N * 102;            // u16 weights
    const size_t G0 = F0 + 3100672;                    // CSR

    float* xa  = ws + A0;
    float* hF  = ws + A0;
    float* b1  = ws + A0;
    unsigned short* cenc = (unsigned short*)(ws + B0);
    unsigned short* cdec = (unsigned short*)(ws + B0);
    unsigned short* zb   = cdec + (size_t)N * 544;
    unsigned short* xbf  = (unsigned short*)(ws + C0);  // dead before a1 written
    float* a1 = ws + C0;
    unsigned short* hbf  = (unsigned short*)(ws + C0);
    unsigned short* encb = hbf + (size_t)N * 512;
    unsigned short* decb = (unsigned short*)(ws + C0);
    float* a2 = ws + D0;
    float* b2 = ws + D0;
    float* a3 = ws + E0;
    float* b3 = ws + E0;
    unsigned short* wF = (unsigned short*)(ws + F0);
    unsigned short* BceT   = wF;                       // 512*800
    unsigned short* BcdT   = BceT + 512 * 800;         // 768*544
    unsigned short* WdencT = BcdT + 768 * 544;         // 20*256*512
    unsigned short* WddecT = WdencT + 20 * 256 * 512;  // 20*512*256
    unsigned short* WmuT   = WddecT + 20 * 512 * 256;  // 256*256
    unsigned short* WlvT   = WmuT + 256 * 256;
    int*   csr_cnt  = (int*)(ws + G0);
    int*   csr_offs = csr_cnt + N;
    int*   csr_cur  = csr_offs + N + 1;
    int*   csr_col  = csr_cur + N;
    float* csr_val  = (float*)(csr_col + E);

    float* out_recon = (float*)d_out;
    float* out_mu    = out_recon + (size_t)N * 768;
    float* out_lv    = out_mu + (size_t)N * 256;

    // --- packs + cast (independent) ---
    {
        Bounds be = {{0, 54, 108, 210, 407, 794}};
        pack_basis_T<<<(512 * 800 + 255) / 256, 256, 0, stream>>>(basisenc, BceT, be, 768, 512, 794, 800);
        Bounds bdd = {{0, 38, 76, 146, 279, 538}};
        pack_basis_T<<<(768 * 544 + 255) / 256, 256, 0, stream>>>(basisdec, BcdT, bdd, 512, 768, 538, 544);
        pack_wT<<<(20 * 256 * 512 + 255) / 256, 256, 0, stream>>>(Wd_enc, WdencT, 20, 512, 256, 512);
        pack_wT<<<(20 * 512 * 256 + 255) / 256, 256, 0, stream>>>(Wd_dec, WddecT, 20, 256, 512, 256);
        pack_wT<<<(256 * 256 + 255) / 256, 256, 0, stream>>>(W_mu, WmuT, 1, 256, 256, 256);
        pack_wT<<<(256 * 256 + 255) / 256, 256, 0, stream>>>(W_lv, WlvT, 1, 256, 256, 256);
        cast_bf16_kernel<<<(N * 768 / 4 + 255) / 256, 256, 0, stream>>>(x, xbf, N * 768 / 4);
    }

    // 1) SpMM via device-built CSR (bf16 gather)
    hipMemsetAsync(csr_cnt, 0, N * sizeof(int), stream);
    hipMemsetAsync(cenc, 0, (size_t)N * 800 * sizeof(unsigned short), stream);
    hist_kernel<<<(E + 255) / 256, 256, 0, stream>>>(arows, csr_cnt, E);
    scan_kernel<<<1, 1024, 0, stream>>>(csr_cnt, csr_offs, csr_cur, N, E);
    scatter_kernel<<<(E + 255) / 256, 256, 0, stream>>>(arows, acols, avals, csr_cur, csr_col, csr_val, E);
    spmm_csr<<<N / 4, 256, 0, stream>>>(xbf, csr_offs, csr_col, csr_val, xa);

    // 2) wavedec enc: 768->387->197->102->54 ; cenc cols [cA4(0)|cD4(54)|cD3(108)|cD2(210)|cD1(407)]
    dwt_kernel<false, false><<<N, 128, 768 * 4, stream>>>(xa, 768, 768, a1, 387, cenc + 407, 800, 387);
    dwt_kernel<false, false><<<N, 128, 387 * 4, stream>>>(a1, 387, 387, a2, 197, cenc + 210, 800, 197);
    dwt_kernel<false, false><<<N, 128, 197 * 4, stream>>>(a2, 197, 197, a3, 102, cenc + 108, 800, 102);
    dwt_kernel<false, true><<<N, 128, 102 * 4, stream>>>(a3, 102, 102, cenc + 0, 800, cenc + 54, 800, 54);

    // 3) h = cenc @ BceT^T  [16384,512], K=800
    gemm_mfma<0><<<dim3(512 / 128, N / 128), 256, 0, stream>>>(cenc, BceT, nullptr, hF, N, 512, 800, 800, 800, 512);

    // 4) layernorm -> bf16
    layernorm_bf16<<<N, 256, 0, stream>>>(hF, hbf, ln_g, ln_b);

    // 5) enc = max_kb gelu(hbf @ Wd_enc[kb]) -> bf16, fused pipelined
    dendritic_fused<512><<<dim3(256 / 128, N / 128), 256, 0, stream>>>(hbf, WdencT, bd_enc, encb, 256, 20);

    // 6) mu / logvar (f32 out to d_out), K=256
    gemm_mfma<0><<<dim3(256 / 128, N / 128), 256, 0, stream>>>(encb, WmuT, b_mu, out_mu, N, 256, 256, 256, 256, 256);
    gemm_mfma<0><<<dim3(256 / 128, N / 128), 256, 0, stream>>>(encb, WlvT, b_lv, out_lv, N, 256, 256, 256, 256, 256);

    // 7) z -> bf16
    z_kernel<<<(N * 256 / 4 + 255) / 256, 256, 0, stream>>>(out_mu, out_lv, epsin, zb, N * 256 / 4);

    // 8) dec = max_kb gelu(zb @ Wd_dec[kb]) -> bf16, fused pipelined
    dendritic_fused<256><<<dim3(512 / 128, N / 128), 256, 0, stream>>>(zb, WddecT, bd_dec, decb, 512, 20);

    // 9) memset cdec pad, then wavedec dec: 512->259->133->70->38 ; cols [0|38|76|146|279]
    hipMemsetAsync(cdec, 0, (size_t)N * 544 * sizeof(unsigned short), stream);
    dwt_kernel<true, false><<<N, 128, 512 * 4, stream>>>(decb, 512, 512, b1, 259, cdec + 279, 544, 259);
    dwt_kernel<false, false><<<N, 128, 259 * 4, stream>>>(b1, 259, 259, b2, 133, cdec + 146, 544, 133);
    dwt_kernel<false, false><<<N, 128, 133 * 4, stream>>>(b2, 133, 133, b3, 70, cdec + 76, 544, 70);
    dwt_kernel<false, true><<<N, 128, 70 * 4, stream>>>(b3, 70, 70, cdec + 0, 544, cdec + 38, 544, 38);

    // 10) recon = cdec @ BcdT^T [16384,768], K=544
    gemm_mfma<0><<<dim3(768 / 128, N / 128), 256, 0, stream>>>(cdec, BcdT, nullptr, out_recon, N, 768, 544, 544, 544, 768);

    (void)ws_size; (void)out_size; (void)n_in;
}